// Round 1
// baseline (245.805 us; speedup 1.0000x reference)
//
#include <hip/hip_runtime.h>
#include <hip/hip_bf16.h>
#include <stdint.h>

// Problem constants
#define Bn   32
#define CIN  128
#define Hh   56
#define Ww   56
#define COUT 256
#define HP   58      // padded H (1 each side)
#define WP   58      // padded W
#define KTOT 1152    // 3*3*128, k = kh*384 + kw*128 + ci
#define NTOT (Bn * Hh * Ww)   // 100352

typedef __attribute__((ext_vector_type(8))) short short8;     // 8 x bf16
typedef __attribute__((ext_vector_type(4))) float floatx4;

__device__ __forceinline__ void async_copy16(const void* g, void* l) {
  // global -> LDS direct copy, 16B per lane; LDS dest = wave-uniform base + lane*16
  __builtin_amdgcn_global_load_lds(
      (const __attribute__((address_space(1))) uint32_t*)g,
      (__attribute__((address_space(3))) uint32_t*)l, 16, 0, 0);
}

// ---------------------------------------------------------------------------
// Pre-pass 1: x NCHW fp32 -> zero-padded NHWC bf16  xpad[b][hp][wp][ci]
// One block per (b, hp). LDS transpose so reads (along w) and writes (along ci)
// are both coalesced.
// ---------------------------------------------------------------------------
__global__ __launch_bounds__(256) void xform_x(const float* __restrict__ x,
                                               __hip_bfloat16* __restrict__ xp) {
  __shared__ __hip_bfloat16 t[Ww * 130];   // [w][ci], stride 130 kills bank conflicts
  const int bid = blockIdx.x;
  const int b = bid / HP, hp = bid % HP;
  const size_t obase = ((size_t)(b * HP + hp)) * WP * CIN;
  const int tid = threadIdx.x;

  if (hp == 0 || hp == HP - 1) {            // top/bottom padding rows
    for (int i = tid; i < WP * CIN; i += 256) xp[obase + i] = __float2bfloat16(0.0f);
    return;
  }
  const int h = hp - 1;
  for (int idx = tid; idx < CIN * Ww; idx += 256) {
    const int ci = idx / Ww, w = idx - ci * Ww;
    const float v = x[(((size_t)b * CIN + ci) * Hh + h) * Ww + w];
    t[w * 130 + ci] = __float2bfloat16(v);
  }
  // left/right padding columns
  if (tid < CIN) {
    xp[obase + tid] = __float2bfloat16(0.0f);
    xp[obase + (size_t)(WP - 1) * CIN + tid] = __float2bfloat16(0.0f);
  }
  __syncthreads();
  for (int idx = tid; idx < Ww * CIN; idx += 256) {
    const int w = idx >> 7, ci = idx & 127;
    xp[obase + (size_t)(w + 1) * CIN + ci] = t[w * 130 + ci];
  }
}

// ---------------------------------------------------------------------------
// Pre-pass 2: weights OIHW fp32 -> wt[co][kh][kw][ci] bf16 (row-major 256x1152)
// ---------------------------------------------------------------------------
__global__ __launch_bounds__(256) void xform_w(const float* __restrict__ w,
                                               __hip_bfloat16* __restrict__ wt) {
  const int idx = blockIdx.x * 256 + threadIdx.x;   // grid sized exactly 256*1152
  const int co = idx / KTOT, k = idx - co * KTOT;
  const int kh = k / 384, r = k - kh * 384, kw = r >> 7, ci = r & 127;
  wt[idx] = __float2bfloat16(w[((co * CIN + ci) * 3 + kh) * 3 + kw]);
}

// ---------------------------------------------------------------------------
// Implicit GEMM: C[m=co][n=(b,h,w)] = sum_k A[m][k] * B[k][n] + bias
//   A = wt (256 x 1152 bf16, row-major)
//   B[k][n] = xpad[b][h+kh][w+kw][ci]  (contiguous in k within each 32-chunk)
// 128x128 block tile, BK=32, 4 waves of 4x4 16x16x32 bf16 MFMA (m97 structure).
// ---------------------------------------------------------------------------
__global__ __launch_bounds__(256) void conv_gemm(const __hip_bfloat16* __restrict__ wt,
                                                 const __hip_bfloat16* __restrict__ xp,
                                                 const float* __restrict__ bias,
                                                 float* __restrict__ y) {
  __shared__ __align__(16) __hip_bfloat16 At[128 * 32];  // [m][k] 8KB
  __shared__ __align__(16) __hip_bfloat16 Bt[128 * 32];  // [n][k] 8KB

  const int tid  = threadIdx.x;
  const int lane = tid & 63, wv = tid >> 6;
  const int bm = blockIdx.x & 1;         // 2 m-tiles; paired so both share B in L2
  const int bn = blockIdx.x >> 1;        // 784 n-tiles
  const int m0 = bm * 128, n0 = bn * 128;

  // ---- staging assignment: each thread owns 16B at LDS offset chunk*4096 + tid*16
  const int sr   = wv * 16 + (lane >> 2);    // tile row (0..63), +64 for chunk 1
  const int kofs = (lane & 3) * 8;           // k element offset within BK
  const __hip_bfloat16* aP0 = wt + (size_t)(m0 + sr) * KTOT + kofs;
  const __hip_bfloat16* aP1 = wt + (size_t)(m0 + sr + 64) * KTOT + kofs;

  const int n_r0 = n0 + sr, n_r1 = n_r0 + 64;
  const int b0 = n_r0 / 3136, r0 = n_r0 - b0 * 3136, h0 = r0 / 56, w0 = r0 - h0 * 56;
  const int b1 = n_r1 / 3136, r1 = n_r1 - b1 * 3136, h1 = r1 / 56, w1 = r1 - h1 * 56;
  const int pb0 = (b0 * HP + h0) * WP + w0;  // pixel index in xpad (pad offset folded in)
  const int pb1 = (b1 * HP + h1) * WP + w1;

  char* ldsA = (char*)At + wv * 1024;
  char* ldsB = (char*)Bt + wv * 1024;

  // ---- fragment read pointers (fixed across K loop; LDS contents change)
  const int fm = lane & 15, fk = (lane >> 4) * 8;
  const int waveM = wv & 1, waveN = wv >> 1;
  const short8* aF[4];
  const short8* bF[4];
#pragma unroll
  for (int i = 0; i < 4; ++i) {
    aF[i] = (const short8*)&At[(waveM * 64 + i * 16 + fm) * 32 + fk];
    bF[i] = (const short8*)&Bt[(waveN * 64 + i * 16 + fm) * 32 + fk];
  }

  floatx4 acc[4][4];
#pragma unroll
  for (int i = 0; i < 4; ++i)
#pragma unroll
    for (int j = 0; j < 4; ++j) acc[i][j] = (floatx4){0.f, 0.f, 0.f, 0.f};

  for (int kt = 0; kt < 36; ++kt) {
    // k0 = kt*32 -> (kh, kw, ci0); each BK=32 chunk has fixed (kh,kw)
    const int kh = kt / 12, rr = kt - kh * 12, kw = rr >> 2, ci0 = (kt & 3) * 32;
    const int bOff = (kh * WP + kw) * CIN + ci0 + kofs;

    async_copy16(aP0 + kt * 32, ldsA);
    async_copy16(aP1 + kt * 32, ldsA + 4096);
    async_copy16(xp + (size_t)pb0 * CIN + bOff, ldsB);
    async_copy16(xp + (size_t)pb1 * CIN + bOff, ldsB + 4096);
    __syncthreads();   // drains vmcnt, staging visible

    short8 a[4], b[4];
#pragma unroll
    for (int i = 0; i < 4; ++i) a[i] = aF[i][0];
#pragma unroll
    for (int j = 0; j < 4; ++j) b[j] = bF[j][0];
#pragma unroll
    for (int i = 0; i < 4; ++i)
#pragma unroll
      for (int j = 0; j < 4; ++j)
        acc[i][j] = __builtin_amdgcn_mfma_f32_16x16x32_bf16(a[i], b[j], acc[i][j], 0, 0, 0);
    __syncthreads();   // all reads done before next stage overwrites LDS
  }

  // ---- epilogue: D[row][col], col = lane&15 (n), row = (lane>>4)*4 + reg (m)
  const int col = lane & 15, quad = lane >> 4;
#pragma unroll
  for (int j = 0; j < 4; ++j) {
    const int n = n0 + waveN * 64 + j * 16 + col;
    const int bb = n / 3136, nr = n - bb * 3136;
    const size_t base = (size_t)bb * (COUT * 3136) + nr;
#pragma unroll
    for (int i = 0; i < 4; ++i) {
      const int co0 = m0 + waveM * 64 + i * 16 + quad * 4;
      const floatx4 b4 = *(const floatx4*)&bias[co0];
#pragma unroll
      for (int r = 0; r < 4; ++r) {
        y[base + (size_t)(co0 + r) * 3136] = acc[i][j][r] + b4[r];
      }
    }
  }
}

extern "C" void kernel_launch(void* const* d_in, const int* in_sizes, int n_in,
                              void* d_out, int out_size, void* d_ws, size_t ws_size,
                              hipStream_t stream) {
  const float* x = (const float*)d_in[0];
  const float* w = (const float*)d_in[1];
  const float* b = (const float*)d_in[2];
  float* y = (float*)d_out;

  const size_t xpad_bytes = (size_t)Bn * HP * WP * CIN * sizeof(__hip_bfloat16); // 27.55 MB
  __hip_bfloat16* xp = (__hip_bfloat16*)d_ws;
  __hip_bfloat16* wt = (__hip_bfloat16*)((char*)d_ws + xpad_bytes);              // +0.59 MB

  xform_x<<<Bn * HP, 256, 0, stream>>>(x, xp);
  xform_w<<<(COUT * KTOT) / 256, 256, 0, stream>>>(w, wt);
  conv_gemm<<<2 * (NTOT / 128), 256, 0, stream>>>(wt, xp, b, y);
}

// Round 2
// 242.993 us; speedup vs baseline: 1.0116x; 1.0116x over previous
//
#include <hip/hip_runtime.h>
#include <hip/hip_bf16.h>
#include <stdint.h>

// Problem constants
#define Bn   32
#define CIN  128
#define Hh   56
#define Ww   56
#define COUT 256
#define HP   58      // padded H (1 each side)
#define WP   58      // padded W
#define KTOT 1152    // 3*3*128, k = kh*384 + kw*128 + ci
#define NTOT (Bn * Hh * Ww)   // 100352

typedef __attribute__((ext_vector_type(8))) short short8;     // 8 x bf16
typedef __attribute__((ext_vector_type(4))) float floatx4;

__device__ __forceinline__ void async_copy16(const void* g, void* l) {
  // global -> LDS direct copy, 16B per lane; LDS dest = wave-uniform base + lane*16
  __builtin_amdgcn_global_load_lds(
      (const __attribute__((address_space(1))) uint32_t*)g,
      (__attribute__((address_space(3))) uint32_t*)l, 16, 0, 0);
}

// ---------------------------------------------------------------------------
// Pre-pass 1 (v2, vectorized): x NCHW fp32 -> zero-padded NHWC bf16
//   xpad[b][hp][wp][ci].  One block per (b, hp).
//   float4 coalesced reads -> LDS transpose [w_out][ci] (pad cols zeroed in
//   LDS) -> uint4 (8 bf16) coalesced 16B stores.
// ---------------------------------------------------------------------------
__global__ __launch_bounds__(256) void xform_x(const float* __restrict__ x,
                                               __hip_bfloat16* __restrict__ xp) {
  __shared__ __hip_bfloat16 t[WP * 130];   // [w_out][ci], stride 130 (4B-aligned rows)
  const int bid = blockIdx.x;
  const int b = bid / HP, hp = bid % HP;
  const size_t obase = (size_t)bid * (WP * CIN);
  const int tid = threadIdx.x;

  if (hp == 0 || hp == HP - 1) {            // top/bottom padding rows: 14848B of zeros
    uint4 z = {0u, 0u, 0u, 0u};
    uint4* o = (uint4*)(xp + obase);
    for (int i = tid; i < (WP * CIN) / 8; i += 256) o[i] = z;
    return;
  }
  const int h = hp - 1;

  // zero the left/right pad columns (t rows 0 and 57)
  {
    const int r = (tid >> 7) * (WP - 1);    // tid<128 -> row 0, else row 57
    const int ci = tid & 127;
    t[r * 130 + ci] = __float2bfloat16(0.0f);
  }

  // fill t rows 1..56 from x: float4 along w, transpose into [w][ci]
  const float* xrow = x + (size_t)b * (CIN * Hh * Ww) + h * Ww;
  for (int i = tid; i < CIN * 14; i += 256) {   // 14 float4 per ci row
    const int ci = i / 14, wq = i - ci * 14;
    const float4 v = *(const float4*)(xrow + (size_t)ci * (Hh * Ww) + wq * 4);
    const int wr = 1 + wq * 4;
    t[(wr + 0) * 130 + ci] = __float2bfloat16(v.x);
    t[(wr + 1) * 130 + ci] = __float2bfloat16(v.y);
    t[(wr + 2) * 130 + ci] = __float2bfloat16(v.z);
    t[(wr + 3) * 130 + ci] = __float2bfloat16(v.w);
  }
  __syncthreads();

  // write out: 8 bf16 (16B) per chunk, ci-contiguous, coalesced
  for (int i = tid; i < (WP * CIN) / 8; i += 256) {
    const int wo = i >> 4, c8 = (i & 15) * 8;
    const uint32_t* src = (const uint32_t*)&t[wo * 130 + c8];  // 4B-aligned (130 even, c8 mult of 8)
    uint4 d;
    d.x = src[0]; d.y = src[1]; d.z = src[2]; d.w = src[3];
    *(uint4*)(xp + obase + (size_t)wo * CIN + c8) = d;
  }
}

// ---------------------------------------------------------------------------
// Pre-pass 2: weights OIHW fp32 -> wt[co][kh][kw][ci] bf16 (row-major 256x1152)
// ---------------------------------------------------------------------------
__global__ __launch_bounds__(256) void xform_w(const float* __restrict__ w,
                                               __hip_bfloat16* __restrict__ wt) {
  const int idx = blockIdx.x * 256 + threadIdx.x;   // grid sized exactly 256*1152
  const int co = idx / KTOT, k = idx - co * KTOT;
  const int kh = k / 384, r = k - kh * 384, kw = r >> 7, ci = r & 127;
  wt[idx] = __float2bfloat16(w[((co * CIN + ci) * 3 + kh) * 3 + kw]);
}

// ---------------------------------------------------------------------------
// Implicit GEMM: C[m=co][n=(b,h,w)] = sum_k A[m][k] * B[k][n] + bias
//   A = wt (256 x 1152 bf16, row-major)
//   B[k][n] = xpad[b][h+kh][w+kw][ci]  (contiguous in k within each 64-chunk)
// 128x128 block tile, BK=64 (two [128][32] sub-tiles per operand per iter ->
// half the barrier-drains of BK=32), 4 waves of 4x4 16x16x32 bf16 MFMA.
// ---------------------------------------------------------------------------
__global__ __launch_bounds__(256) void conv_gemm(const __hip_bfloat16* __restrict__ wt,
                                                 const __hip_bfloat16* __restrict__ xp,
                                                 const float* __restrict__ bias,
                                                 float* __restrict__ y) {
  __shared__ __align__(16) __hip_bfloat16 At[2][128 * 32];  // [s][m][k] 16KB
  __shared__ __align__(16) __hip_bfloat16 Bt[2][128 * 32];  // [s][n][k] 16KB

  const int tid  = threadIdx.x;
  const int lane = tid & 63, wv = tid >> 6;
  const int bm = blockIdx.x & 1;         // 2 m-tiles; paired so both share B in L2
  const int bn = blockIdx.x >> 1;        // 784 n-tiles
  const int m0 = bm * 128, n0 = bn * 128;

  // ---- staging assignment: each thread owns 16B at LDS offset chunk*4096 + tid*16
  const int sr   = wv * 16 + (lane >> 2);    // tile row (0..63), +64 for chunk 1
  const int kofs = (lane & 3) * 8;           // k element offset within 32-subchunk
  const __hip_bfloat16* aP0 = wt + (size_t)(m0 + sr) * KTOT + kofs;
  const __hip_bfloat16* aP1 = wt + (size_t)(m0 + sr + 64) * KTOT + kofs;

  const int n_r0 = n0 + sr, n_r1 = n_r0 + 64;
  const int b0 = n_r0 / 3136, r0 = n_r0 - b0 * 3136, h0 = r0 / 56, w0 = r0 - h0 * 56;
  const int b1 = n_r1 / 3136, r1 = n_r1 - b1 * 3136, h1 = r1 / 56, w1 = r1 - h1 * 56;
  const int pb0 = (b0 * HP + h0) * WP + w0;  // pixel index in xpad (pad offset folded in)
  const int pb1 = (b1 * HP + h1) * WP + w1;
  const __hip_bfloat16* bP0 = xp + (size_t)pb0 * CIN + kofs;
  const __hip_bfloat16* bP1 = xp + (size_t)pb1 * CIN + kofs;

  char* ldsA = (char*)At + wv * 1024;
  char* ldsB = (char*)Bt + wv * 1024;

  // ---- fragment read pointers (fixed across K loop; LDS contents change)
  const int fm = lane & 15, fk = (lane >> 4) * 8;
  const int waveM = wv & 1, waveN = wv >> 1;
  const short8* aF[4];
  const short8* bF[4];
#pragma unroll
  for (int i = 0; i < 4; ++i) {
    aF[i] = (const short8*)&At[0][(waveM * 64 + i * 16 + fm) * 32 + fk];
    bF[i] = (const short8*)&Bt[0][(waveN * 64 + i * 16 + fm) * 32 + fk];
  }

  floatx4 acc[4][4];
#pragma unroll
  for (int i = 0; i < 4; ++i)
#pragma unroll
    for (int j = 0; j < 4; ++j) acc[i][j] = (floatx4){0.f, 0.f, 0.f, 0.f};

  for (int kt = 0; kt < 18; ++kt) {
    // k0 = kt*64 -> (kh, kw, ci0); each BK=64 chunk has fixed (kh,kw)
    const int kh = kt / 6, rr = kt - kh * 6, kw = rr >> 1, ci0 = (kt & 1) * 64;
    const int bOff = (kh * WP + kw) * CIN + ci0;

#pragma unroll
    for (int s = 0; s < 2; ++s) {
      async_copy16(aP0 + kt * 64 + s * 32, ldsA + s * 8192);
      async_copy16(aP1 + kt * 64 + s * 32, ldsA + s * 8192 + 4096);
      async_copy16(bP0 + bOff + s * 32, ldsB + s * 8192);
      async_copy16(bP1 + bOff + s * 32, ldsB + s * 8192 + 4096);
    }
    __syncthreads();   // drains vmcnt, staging visible

#pragma unroll
    for (int s = 0; s < 2; ++s) {
      short8 a[4], b[4];
#pragma unroll
      for (int i = 0; i < 4; ++i) a[i] = aF[i][s * 512];   // At[s] is 4096 bf16 = 512 short8 apart
#pragma unroll
      for (int j = 0; j < 4; ++j) b[j] = bF[j][s * 512];
#pragma unroll
      for (int i = 0; i < 4; ++i)
#pragma unroll
        for (int j = 0; j < 4; ++j)
          acc[i][j] = __builtin_amdgcn_mfma_f32_16x16x32_bf16(a[i], b[j], acc[i][j], 0, 0, 0);
    }
    __syncthreads();   // all reads done before next stage overwrites LDS
  }

  // ---- epilogue: D[row][col], col = lane&15 (n), row = (lane>>4)*4 + reg (m)
  const int col = lane & 15, quad = lane >> 4;
#pragma unroll
  for (int j = 0; j < 4; ++j) {
    const int n = n0 + waveN * 64 + j * 16 + col;
    const int bb = n / 3136, nr = n - bb * 3136;
    const size_t base = (size_t)bb * (COUT * 3136) + nr;
#pragma unroll
    for (int i = 0; i < 4; ++i) {
      const int co0 = m0 + waveM * 64 + i * 16 + quad * 4;
      const floatx4 b4 = *(const floatx4*)&bias[co0];
#pragma unroll
      for (int r = 0; r < 4; ++r) {
        y[base + (size_t)(co0 + r) * 3136] = acc[i][j][r] + b4[r];
      }
    }
  }
}

extern "C" void kernel_launch(void* const* d_in, const int* in_sizes, int n_in,
                              void* d_out, int out_size, void* d_ws, size_t ws_size,
                              hipStream_t stream) {
  const float* x = (const float*)d_in[0];
  const float* w = (const float*)d_in[1];
  const float* b = (const float*)d_in[2];
  float* y = (float*)d_out;

  const size_t xpad_bytes = (size_t)Bn * HP * WP * CIN * sizeof(__hip_bfloat16); // 27.55 MB
  __hip_bfloat16* xp = (__hip_bfloat16*)d_ws;
  __hip_bfloat16* wt = (__hip_bfloat16*)((char*)d_ws + xpad_bytes);              // +0.59 MB

  xform_x<<<Bn * HP, 256, 0, stream>>>(x, xp);
  xform_w<<<(COUT * KTOT) / 256, 256, 0, stream>>>(w, wt);
  conv_gemm<<<2 * (NTOT / 128), 256, 0, stream>>>(wt, xp, b, y);
}